// Round 1
// baseline (49690.244 us; speedup 1.0000x reference)
//
#include <hip/hip_runtime.h>
#include <hip/hip_bf16.h>

#define Hd 768
#define Bd 32
#define Td 1024
#define Md (Bd*Td)

#define NWG_SCAN 256
#define GPB 12   // g-rows per scan WG
#define BPB 8    // batches per scan WG
#define KCH 48   // K-chunk per thread (768/16)

// ---------------- init: h0 copy + barrier reset ----------------
__global__ __launch_bounds__(256) void k_init(const float* __restrict__ hid,
                                              float* __restrict__ hbuf,
                                              unsigned* __restrict__ cnt) {
    int i = blockIdx.x * 256 + threadIdx.x;
    if (i < Bd * Hd) hbuf[i] = hid[i];
    if (blockIdx.x == 0 && threadIdx.x == 0) *cnt = 0u;
}

// ---------------- phase 1: gi_r / gi_n GEMM ----------------
// gi_r[m,g] = sum_k A[m,k]*Wih[g,k]      + bih[g]
// gi_n[m,g] = sum_k A[m,k]*Wih[2H+g,k]   + bih[2H+g]
__global__ __launch_bounds__(256, 2) void k_gemm(const float* __restrict__ A,
                                                 const float* __restrict__ Wih,
                                                 const float* __restrict__ bih,
                                                 float* __restrict__ giR,
                                                 float* __restrict__ giN) {
    __shared__ float As[16][68];
    __shared__ float Brs[16][68];
    __shared__ float Bns[16][68];
    const int tid = threadIdx.x;
    const int mb = blockIdx.x & 511;   // 512 m-tiles
    const int nb = blockIdx.x >> 9;    // 12 n-tiles
    const int lm = tid >> 2;           // 0..63
    const int lk = (tid & 3) << 2;     // 0,4,8,12
    const int tx = tid & 15;
    const int ty = tid >> 4;

    const float* pA = A   + (size_t)(mb * 64 + lm) * Hd + lk;
    const float* pR = Wih + (size_t)(nb * 64 + lm) * Hd + lk;
    const float* pN = Wih + (size_t)(2 * Hd + nb * 64 + lm) * Hd + lk;

    float accR[4][4] = {{0.f}};
    float accN[4][4] = {{0.f}};

    for (int kt = 0; kt < Hd; kt += 16) {
        float4 va = *(const float4*)(pA + kt);
        float4 vr = *(const float4*)(pR + kt);
        float4 vn = *(const float4*)(pN + kt);
        __syncthreads();
        As[lk+0][lm]=va.x; As[lk+1][lm]=va.y; As[lk+2][lm]=va.z; As[lk+3][lm]=va.w;
        Brs[lk+0][lm]=vr.x; Brs[lk+1][lm]=vr.y; Brs[lk+2][lm]=vr.z; Brs[lk+3][lm]=vr.w;
        Bns[lk+0][lm]=vn.x; Bns[lk+1][lm]=vn.y; Bns[lk+2][lm]=vn.z; Bns[lk+3][lm]=vn.w;
        __syncthreads();
        #pragma unroll
        for (int k = 0; k < 16; ++k) {
            float4 a4 = *(const float4*)&As[k][ty << 2];
            float4 r4 = *(const float4*)&Brs[k][tx << 2];
            float4 n4 = *(const float4*)&Bns[k][tx << 2];
            float av[4] = {a4.x, a4.y, a4.z, a4.w};
            float rv[4] = {r4.x, r4.y, r4.z, r4.w};
            float nv[4] = {n4.x, n4.y, n4.z, n4.w};
            #pragma unroll
            for (int i = 0; i < 4; ++i)
                #pragma unroll
                for (int j = 0; j < 4; ++j) {
                    accR[i][j] += av[i] * rv[j];
                    accN[i][j] += av[i] * nv[j];
                }
        }
    }

    const int m0 = mb * 64 + (ty << 2);
    const int g0 = nb * 64 + (tx << 2);
    float4 bR = *(const float4*)(bih + g0);
    float4 bN = *(const float4*)(bih + 2 * Hd + g0);
    #pragma unroll
    for (int i = 0; i < 4; ++i) {
        float4 oR = { accR[i][0]+bR.x, accR[i][1]+bR.y, accR[i][2]+bR.z, accR[i][3]+bR.w };
        float4 oN = { accN[i][0]+bN.x, accN[i][1]+bN.y, accN[i][2]+bN.z, accN[i][3]+bN.w };
        *(float4*)(giR + (size_t)(m0 + i) * Hd + g0) = oR;
        *(float4*)(giN + (size_t)(m0 + i) * Hd + g0) = oN;
    }
}

// ---------------- phase 2: persistent sequential scan ----------------
// 256 WGs x 192 threads. WG = (b-block bb of 8, g-block gb of 12).
// thread = (gl 0..11, ks 0..15); W rows stationary in VGPRs (48 k x 2 gates);
// h staged in LDS each step; 16-lane shuffle reduce over ks; one global
// barrier (monotonic counter) per step.
__global__ __launch_bounds__(192, 1) void k_scan(const float* __restrict__ Whh,
                                                 const float* __restrict__ bhh,
                                                 const float* __restrict__ giR,
                                                 float* __restrict__ out,   // holds giN, overwritten with h
                                                 float* __restrict__ hbuf,  // 2 * B * H
                                                 unsigned* __restrict__ cnt) {
    __shared__ float hs[BPB][Hd];
    const int tid = threadIdx.x;
    const int gl  = tid >> 4;          // 0..11
    const int ks  = tid & 15;          // 0..15
    const int gb  = blockIdx.x >> 2;   // 0..63
    const int bb  = blockIdx.x & 3;    // 0..3
    const int g   = gb * GPB + gl;     // 0..767
    const int k0  = ks * KCH;          // 0..720

    // stationary weight slices in registers (loaded once)
    float wr[KCH], wn[KCH];
    {
        const float* pr = Whh + (size_t)g * Hd + k0;
        const float* pn = Whh + (size_t)(2 * Hd + g) * Hd + k0;
        #pragma unroll
        for (int j = 0; j < KCH / 4; ++j) {
            float4 a = *(const float4*)(pr + j * 4);
            float4 b = *(const float4*)(pn + j * 4);
            wr[j*4+0]=a.x; wr[j*4+1]=a.y; wr[j*4+2]=a.z; wr[j*4+3]=a.w;
            wn[j*4+0]=b.x; wn[j*4+1]=b.y; wn[j*4+2]=b.z; wn[j*4+3]=b.w;
        }
    }
    const float bhr = bhh[g];
    const float bhn = bhh[2 * Hd + g];

    for (int t = 0; t < Td; ++t) {
        if (t > 0) {
            if (tid == 0) {
                const unsigned tgt = (unsigned)(NWG_SCAN * t);
                while (__hip_atomic_load(cnt, __ATOMIC_ACQUIRE, __HIP_MEMORY_SCOPE_AGENT) < tgt)
                    __builtin_amdgcn_s_sleep(1);
            }
            __syncthreads();
            __threadfence();   // acquire: invalidate so h reads are fresh
        }
        const float* hsrc = hbuf + (size_t)(t & 1) * (Bd * Hd);
        float*       hdst = hbuf + (size_t)((t + 1) & 1) * (Bd * Hd);

        // stage this WG's 8 h-rows into LDS (coalesced, conflict-free)
        #pragma unroll
        for (int i = 0; i < BPB; ++i) {
            float4 v = *(const float4*)(hsrc + (size_t)(bb * BPB + i) * Hd + (tid << 2));
            *(float4*)&hs[i][tid << 2] = v;
        }
        __syncthreads();

        for (int i = 0; i < BPB; ++i) {
            float aR = 0.f, aN = 0.f;
            #pragma unroll
            for (int j = 0; j < KCH / 4; ++j) {
                float4 h4 = *(const float4*)&hs[i][k0 + j * 4];
                aR += h4.x * wr[j*4+0]; aN += h4.x * wn[j*4+0];
                aR += h4.y * wr[j*4+1]; aN += h4.y * wn[j*4+1];
                aR += h4.z * wr[j*4+2]; aN += h4.z * wn[j*4+2];
                aR += h4.w * wr[j*4+3]; aN += h4.w * wn[j*4+3];
            }
            #pragma unroll
            for (int off = 8; off >= 1; off >>= 1) {
                aR += __shfl_xor(aR, off);
                aN += __shfl_xor(aN, off);
            }
            if (ks == 0) {
                const int b = bb * BPB + i;
                const size_t mi = (size_t)(b * Td + t) * Hd + g;
                const float gr = giR[mi];
                const float gn = out[mi];     // gi_n, consumed exactly once here
                const float r  = 1.f / (1.f + __expf(-(gr + aR + bhr)));
                const float hn = tanhf(gn + r * (aN + bhn));
                out[mi] = hn;                 // overwrite gi_n with h_t
                hdst[(size_t)b * Hd + g] = hn;
            }
        }

        __threadfence();     // release: make h_new visible device-wide
        __syncthreads();
        if (tid == 0)
            __hip_atomic_fetch_add(cnt, 1u, __ATOMIC_RELEASE, __HIP_MEMORY_SCOPE_AGENT);
    }
}

extern "C" void kernel_launch(void* const* d_in, const int* in_sizes, int n_in,
                              void* d_out, int out_size, void* d_ws, size_t ws_size,
                              hipStream_t stream) {
    const float* input  = (const float*)d_in[0];
    const float* hidden = (const float*)d_in[1];
    const float* Wih    = (const float*)d_in[2];
    const float* Whh    = (const float*)d_in[3];
    const float* bih    = (const float*)d_in[4];
    const float* bhh    = (const float*)d_in[5];
    float* out = (float*)d_out;

    // workspace layout: gi_r (M*H f32) | hbuf (2*B*H f32) | barrier counter
    float*    giR  = (float*)d_ws;
    float*    hbuf = giR + (size_t)Md * Hd;
    unsigned* cnt  = (unsigned*)(hbuf + 2 * Bd * Hd);

    k_init<<<96, 256, 0, stream>>>(hidden, hbuf, cnt);
    k_gemm<<<512 * 12, 256, 0, stream>>>(input, Wih, bih, giR, out);
    k_scan<<<NWG_SCAN, 192, 0, stream>>>(Whh, bhh, giR, out, hbuf, cnt);
}

// Round 2
// 14163.788 us; speedup vs baseline: 3.5083x; 3.5083x over previous
//
#include <hip/hip_runtime.h>
#include <hip/hip_bf16.h>

#define Hd 768
#define Bd 32
#define Td 1024
#define Md (Bd*Td)

// scan config: 4 groups (8 batches each) x 48 WGs (16 g-rows each) = 192 WGs
#define NGRP 4
#define WPG  48     // WGs per group (barrier participants)
#define BPG  8      // batches per group
#define GPW  16     // g-rows per WG
#define CNT_STRIDE 64  // u32 spacing between group counters (256B, no false sharing)

// ---------------- init: h0 copy + barrier counters ----------------
__global__ __launch_bounds__(256) void k_init(const float* __restrict__ hid,
                                              float* __restrict__ hbuf,
                                              unsigned* __restrict__ cnt) {
    int i = blockIdx.x * 256 + threadIdx.x;
    if (i < Bd * Hd) hbuf[i] = hid[i];
    if (blockIdx.x == 0 && threadIdx.x < NGRP) cnt[threadIdx.x * CNT_STRIDE] = 0u;
}

// ---------------- phase 1: gi_r / gi_n GEMM (unchanged from R1) ----------------
__global__ __launch_bounds__(256, 2) void k_gemm(const float* __restrict__ A,
                                                 const float* __restrict__ Wih,
                                                 const float* __restrict__ bih,
                                                 float* __restrict__ giR,
                                                 float* __restrict__ giN) {
    __shared__ float As[16][68];
    __shared__ float Brs[16][68];
    __shared__ float Bns[16][68];
    const int tid = threadIdx.x;
    const int mb = blockIdx.x & 511;
    const int nb = blockIdx.x >> 9;
    const int lm = tid >> 2;
    const int lk = (tid & 3) << 2;
    const int tx = tid & 15;
    const int ty = tid >> 4;

    const float* pA = A   + (size_t)(mb * 64 + lm) * Hd + lk;
    const float* pR = Wih + (size_t)(nb * 64 + lm) * Hd + lk;
    const float* pN = Wih + (size_t)(2 * Hd + nb * 64 + lm) * Hd + lk;

    float accR[4][4] = {{0.f}};
    float accN[4][4] = {{0.f}};

    for (int kt = 0; kt < Hd; kt += 16) {
        float4 va = *(const float4*)(pA + kt);
        float4 vr = *(const float4*)(pR + kt);
        float4 vn = *(const float4*)(pN + kt);
        __syncthreads();
        As[lk+0][lm]=va.x; As[lk+1][lm]=va.y; As[lk+2][lm]=va.z; As[lk+3][lm]=va.w;
        Brs[lk+0][lm]=vr.x; Brs[lk+1][lm]=vr.y; Brs[lk+2][lm]=vr.z; Brs[lk+3][lm]=vr.w;
        Bns[lk+0][lm]=vn.x; Bns[lk+1][lm]=vn.y; Bns[lk+2][lm]=vn.z; Bns[lk+3][lm]=vn.w;
        __syncthreads();
        #pragma unroll
        for (int k = 0; k < 16; ++k) {
            float4 a4 = *(const float4*)&As[k][ty << 2];
            float4 r4 = *(const float4*)&Brs[k][tx << 2];
            float4 n4 = *(const float4*)&Bns[k][tx << 2];
            float av[4] = {a4.x, a4.y, a4.z, a4.w};
            float rv[4] = {r4.x, r4.y, r4.z, r4.w};
            float nv[4] = {n4.x, n4.y, n4.z, n4.w};
            #pragma unroll
            for (int i = 0; i < 4; ++i)
                #pragma unroll
                for (int j = 0; j < 4; ++j) {
                    accR[i][j] += av[i] * rv[j];
                    accN[i][j] += av[i] * nv[j];
                }
        }
    }

    const int m0 = mb * 64 + (ty << 2);
    const int g0 = nb * 64 + (tx << 2);
    float4 bR = *(const float4*)(bih + g0);
    float4 bN = *(const float4*)(bih + 2 * Hd + g0);
    #pragma unroll
    for (int i = 0; i < 4; ++i) {
        float4 oR = { accR[i][0]+bR.x, accR[i][1]+bR.y, accR[i][2]+bR.z, accR[i][3]+bR.w };
        float4 oN = { accN[i][0]+bN.x, accN[i][1]+bN.y, accN[i][2]+bN.z, accN[i][3]+bN.w };
        *(float4*)(giR + (size_t)(m0 + i) * Hd + g0) = oR;
        *(float4*)(giN + (size_t)(m0 + i) * Hd + g0) = oN;
    }
}

// ---------------- phase 2: grouped persistent scan ----------------
// 192 WGs = 4 groups x 48 WGs. Group g owns batches [8g, 8g+8); WG owns 16
// g-rows (all K). Thread = (gl 0..15, ks 0..15); k-set = ks*4 + 64j (2-way
// banks). Weights stationary in VGPRs. h passes through L3 via sc0sc1
// loads/stores (NO fences, NO L2 writeback). Per-group relaxed-counter
// barrier, ordered by explicit s_waitcnt vmcnt(0).
__global__ __launch_bounds__(256, 1) void k_scan(const float* __restrict__ Whh,
                                                 const float* __restrict__ bhh,
                                                 const float* __restrict__ giR,
                                                 float* __restrict__ out,   // giN in, h out
                                                 float* __restrict__ hbuf,  // 2 * B * H
                                                 unsigned* __restrict__ cntbase) {
    __shared__ float hs[BPG][Hd];
    const int tid = threadIdx.x;
    const int gl  = tid >> 4;
    const int ks  = tid & 15;
    const int grp = blockIdx.x / WPG;      // 0..3
    const int gb  = blockIdx.x % WPG;      // 0..47
    const int g   = gb * GPW + gl;         // 0..767
    const int b0  = grp * BPG;
    unsigned* cnt = cntbase + grp * CNT_STRIDE;

    // stationary weights: wr/wn[j*4+c] <-> k = ks*4 + 64*j + c
    float wr[48], wn[48];
    #pragma unroll
    for (int j = 0; j < 12; ++j) {
        float4 a = *(const float4*)(Whh + (size_t)g * Hd + (ks << 2) + (j << 6));
        float4 b = *(const float4*)(Whh + (size_t)(2 * Hd + g) * Hd + (ks << 2) + (j << 6));
        wr[j*4+0]=a.x; wr[j*4+1]=a.y; wr[j*4+2]=a.z; wr[j*4+3]=a.w;
        wn[j*4+0]=b.x; wn[j*4+1]=b.y; wn[j*4+2]=b.z; wn[j*4+3]=b.w;
    }
    const float bhr = bhh[g];
    const float bhn = bhh[2 * Hd + g];

    // gi prefetch registers (ks==0 lanes only)
    float gR[BPG], gN[BPG];
    if (ks == 0) {
        #pragma unroll
        for (int b = 0; b < BPG; ++b) {
            const size_t mi = ((size_t)(b0 + b) * Td) * Hd + g;
            gR[b] = giR[mi];
            gN[b] = out[mi];
        }
    }

    for (int t = 0; t < Td; ++t) {
        if (t > 0) {
            if (tid == 0) {
                const unsigned tgt = (unsigned)(WPG * t);
                while (__hip_atomic_load(cnt, __ATOMIC_RELAXED, __HIP_MEMORY_SCOPE_AGENT) < tgt)
                    __builtin_amdgcn_s_sleep(1);
            }
            __syncthreads();
        }
        const float* hsrc = hbuf + (size_t)(t & 1) * (Bd * Hd) + (size_t)b0 * Hd;
        float*       hdst = hbuf + (size_t)((t + 1) & 1) * (Bd * Hd) + (size_t)b0 * Hd;

        // stage 8x768 h-rows into LDS: 24 coherent (L3) scalar loads/thread
        #pragma unroll
        for (int i = 0; i < 24; ++i) {
            const int w = tid + i * 256;
            ((float*)hs)[w] = __hip_atomic_load(hsrc + w, __ATOMIC_RELAXED,
                                                __HIP_MEMORY_SCOPE_AGENT);
        }
        __syncthreads();

        // prefetch gi[t+1] (plain cached loads; overlaps compute below)
        float gR2[BPG], gN2[BPG];
        if (ks == 0 && t + 1 < Td) {
            #pragma unroll
            for (int b = 0; b < BPG; ++b) {
                const size_t mi = ((size_t)(b0 + b) * Td + (t + 1)) * Hd + g;
                gR2[b] = giR[mi];
                gN2[b] = out[mi];
            }
        }

        // matvec: per thread 8 batches x 48 k x 2 gates
        float accR[BPG], accN[BPG];
        #pragma unroll
        for (int b = 0; b < BPG; ++b) { accR[b] = 0.f; accN[b] = 0.f; }
        #pragma unroll
        for (int b = 0; b < BPG; ++b) {
            #pragma unroll
            for (int j = 0; j < 12; ++j) {
                float4 h4 = *(const float4*)&hs[b][(ks << 2) + (j << 6)];
                accR[b] = fmaf(h4.x, wr[j*4+0], accR[b]);
                accN[b] = fmaf(h4.x, wn[j*4+0], accN[b]);
                accR[b] = fmaf(h4.y, wr[j*4+1], accR[b]);
                accN[b] = fmaf(h4.y, wn[j*4+1], accN[b]);
                accR[b] = fmaf(h4.z, wr[j*4+2], accR[b]);
                accN[b] = fmaf(h4.z, wn[j*4+2], accN[b]);
                accR[b] = fmaf(h4.w, wr[j*4+3], accR[b]);
                accN[b] = fmaf(h4.w, wn[j*4+3], accN[b]);
            }
        }
        // reduce over the 16 ks lanes (butterfly within 16-lane group)
        #pragma unroll
        for (int b = 0; b < BPG; ++b) {
            #pragma unroll
            for (int off = 8; off >= 1; off >>= 1) {
                accR[b] += __shfl_xor(accR[b], off);
                accN[b] += __shfl_xor(accN[b], off);
            }
        }

        if (ks == 0) {
            #pragma unroll
            for (int b = 0; b < BPG; ++b) {
                const float r  = 1.f / (1.f + __expf(-(gR[b] + accR[b] + bhr)));
                const float hn = tanhf(gN[b] + r * (accN[b] + bhn));
                out[((size_t)(b0 + b) * Td + t) * Hd + g] = hn;   // plain (own line)
                __hip_atomic_store(hdst + (size_t)b * Hd + g, hn, __ATOMIC_RELAXED,
                                   __HIP_MEMORY_SCOPE_AGENT);     // through to L3
            }
        }

        // order h-stores before the counter bump; no L2 flush anywhere
        asm volatile("s_waitcnt vmcnt(0)" ::: "memory");
        __syncthreads();
        if (tid == 0)
            __hip_atomic_fetch_add(cnt, 1u, __ATOMIC_RELAXED, __HIP_MEMORY_SCOPE_AGENT);

        if (ks == 0) {
            #pragma unroll
            for (int b = 0; b < BPG; ++b) { gR[b] = gR2[b]; gN[b] = gN2[b]; }
        }
    }
}

extern "C" void kernel_launch(void* const* d_in, const int* in_sizes, int n_in,
                              void* d_out, int out_size, void* d_ws, size_t ws_size,
                              hipStream_t stream) {
    const float* input  = (const float*)d_in[0];
    const float* hidden = (const float*)d_in[1];
    const float* Wih    = (const float*)d_in[2];
    const float* Whh    = (const float*)d_in[3];
    const float* bih    = (const float*)d_in[4];
    const float* bhh    = (const float*)d_in[5];
    float* out = (float*)d_out;

    // ws layout: gi_r (M*H f32) | hbuf (2*B*H f32) | group counters
    float*    giR  = (float*)d_ws;
    float*    hbuf = giR + (size_t)Md * Hd;
    unsigned* cnt  = (unsigned*)(hbuf + 2 * Bd * Hd);

    k_init<<<96, 256, 0, stream>>>(hidden, hbuf, cnt);
    k_gemm<<<512 * 12, 256, 0, stream>>>(input, Wih, bih, giR, out);
    k_scan<<<NGRP * WPG, 256, 0, stream>>>(Whh, bhh, giR, out, hbuf, cnt);
}

// Round 3
// 8385.007 us; speedup vs baseline: 5.9261x; 1.6892x over previous
//
#include <hip/hip_runtime.h>
#include <hip/hip_bf16.h>

#define Hd 768
#define Bd 32
#define Td 1024
#define Md (Bd*Td)

// scan: 16 independent groups (1 batch-pair each) x 16 WGs (48 g-rows each)
#define NPAIR 16
#define SPW   16        // slices (WGs) per group
#define GPW   48        // g-rows per WG
#define RINGD 4         // ring depth (correctness requires >= 4, see protocol)
#define SENT_U 0x7FC00000u   // qNaN sentinel; tanh output bits can never equal it
#define RVALS (2*Hd)    // floats per ring region per group (2 batches x 768)

// ---------------- init: ring region 0 = h0, regions 1..3 = sentinel ----------------
__global__ __launch_bounds__(256) void k_init(const float* __restrict__ hid,
                                              unsigned* __restrict__ ring) {
    int i = blockIdx.x * 256 + threadIdx.x;          // 16*4*1536 = 98304 total
    const int p   = i / (RINGD * RVALS);
    const int rem = i % (RINGD * RVALS);
    const int r   = rem / RVALS;
    const int q   = rem % RVALS;
    const int bb  = q / Hd;
    const int k   = q % Hd;
    unsigned v = SENT_U;
    if (r == 0) v = ((const unsigned*)hid)[(p * 2 + bb) * Hd + k];
    ring[i] = v;
}

// ---------------- phase 1: gi_r / gi_n GEMM (unchanged) ----------------
__global__ __launch_bounds__(256, 2) void k_gemm(const float* __restrict__ A,
                                                 const float* __restrict__ Wih,
                                                 const float* __restrict__ bih,
                                                 float* __restrict__ giR,
                                                 float* __restrict__ giN) {
    __shared__ float As[16][68];
    __shared__ float Brs[16][68];
    __shared__ float Bns[16][68];
    const int tid = threadIdx.x;
    const int mb = blockIdx.x & 511;
    const int nb = blockIdx.x >> 9;
    const int lm = tid >> 2;
    const int lk = (tid & 3) << 2;
    const int tx = tid & 15;
    const int ty = tid >> 4;

    const float* pA = A   + (size_t)(mb * 64 + lm) * Hd + lk;
    const float* pR = Wih + (size_t)(nb * 64 + lm) * Hd + lk;
    const float* pN = Wih + (size_t)(2 * Hd + nb * 64 + lm) * Hd + lk;

    float accR[4][4] = {{0.f}};
    float accN[4][4] = {{0.f}};

    for (int kt = 0; kt < Hd; kt += 16) {
        float4 va = *(const float4*)(pA + kt);
        float4 vr = *(const float4*)(pR + kt);
        float4 vn = *(const float4*)(pN + kt);
        __syncthreads();
        As[lk+0][lm]=va.x; As[lk+1][lm]=va.y; As[lk+2][lm]=va.z; As[lk+3][lm]=va.w;
        Brs[lk+0][lm]=vr.x; Brs[lk+1][lm]=vr.y; Brs[lk+2][lm]=vr.z; Brs[lk+3][lm]=vr.w;
        Bns[lk+0][lm]=vn.x; Bns[lk+1][lm]=vn.y; Bns[lk+2][lm]=vn.z; Bns[lk+3][lm]=vn.w;
        __syncthreads();
        #pragma unroll
        for (int k = 0; k < 16; ++k) {
            float4 a4 = *(const float4*)&As[k][ty << 2];
            float4 r4 = *(const float4*)&Brs[k][tx << 2];
            float4 n4 = *(const float4*)&Bns[k][tx << 2];
            float av[4] = {a4.x, a4.y, a4.z, a4.w};
            float rv[4] = {r4.x, r4.y, r4.z, r4.w};
            float nv[4] = {n4.x, n4.y, n4.z, n4.w};
            #pragma unroll
            for (int i = 0; i < 4; ++i)
                #pragma unroll
                for (int j = 0; j < 4; ++j) {
                    accR[i][j] += av[i] * rv[j];
                    accN[i][j] += av[i] * nv[j];
                }
        }
    }

    const int m0 = mb * 64 + (ty << 2);
    const int g0 = nb * 64 + (tx << 2);
    float4 bR = *(const float4*)(bih + g0);
    float4 bN = *(const float4*)(bih + 2 * Hd + g0);
    #pragma unroll
    for (int i = 0; i < 4; ++i) {
        float4 oR = { accR[i][0]+bR.x, accR[i][1]+bR.y, accR[i][2]+bR.z, accR[i][3]+bR.w };
        float4 oN = { accN[i][0]+bN.x, accN[i][1]+bN.y, accN[i][2]+bN.z, accN[i][3]+bN.w };
        *(float4*)(giR + (size_t)(m0 + i) * Hd + g0) = oR;
        *(float4*)(giN + (size_t)(m0 + i) * Hd + g0) = oN;
    }
}

// ---------------- phase 2: sentinel-ring persistent scan ----------------
// 256 WGs = 16 pairs x 16 slices; thread = (gl 0..15, ks 0..15).
// Protocol per step t:
//   1. reset own slice of region (t+2)%4 to sentinel (safe: h_{t-1} observed
//      last step => everyone consumed h_{t-2} from that region)
//   2. poll-load full h_t (region t%4) until no word is sentinel; stage to LDS
//   3. compute; s_waitcnt vmcnt(0)  (orders reset acks BEFORE produce)
//   4. produce h_{t+1} slice into region (t+1)%4; write out[:,t]
// Any consumer that observes h_{t+1} therefore also observes the reset, so a
// recycled region can never show stale real values.
__global__ __launch_bounds__(256, 1) void k_scan(const float* __restrict__ Whh,
                                                 const float* __restrict__ bhh,
                                                 const float* __restrict__ giR,
                                                 float* __restrict__ out,   // giN in, h out
                                                 unsigned* __restrict__ ring) {
    __shared__ float hs[2][2][Hd];     // parity x batch x k
    const int tid = threadIdx.x;
    const int gl  = tid >> 4;          // 0..15
    const int ks  = tid & 15;          // 0..15
    const int p   = blockIdx.x >> 4;   // pair 0..15
    const int s   = blockIdx.x & 15;   // slice 0..15
    const int b0  = p * 2;
    unsigned* ringp = ring + (size_t)p * RINGD * RVALS;

    // stationary weights: wr/wn[sub][j*4+c] <-> row g=48s+16*sub+gl, k=ks*4+64j+c
    float wr[3][48], wn[3][48];
    int gbase[3];
    #pragma unroll
    for (int sub = 0; sub < 3; ++sub) {
        const int g = s * GPW + sub * 16 + gl;
        gbase[sub] = g;
        #pragma unroll
        for (int j = 0; j < 12; ++j) {
            float4 a = *(const float4*)(Whh + (size_t)g * Hd + (ks << 2) + (j << 6));
            float4 b = *(const float4*)(Whh + (size_t)(2 * Hd + g) * Hd + (ks << 2) + (j << 6));
            wr[sub][j*4+0]=a.x; wr[sub][j*4+1]=a.y; wr[sub][j*4+2]=a.z; wr[sub][j*4+3]=a.w;
            wn[sub][j*4+0]=b.x; wn[sub][j*4+1]=b.y; wn[sub][j*4+2]=b.z; wn[sub][j*4+3]=b.w;
        }
    }
    float br[3], bn[3];
    #pragma unroll
    for (int sub = 0; sub < 3; ++sub) {
        br[sub] = bhh[gbase[sub]];
        bn[sub] = bhh[2 * Hd + gbase[sub]];
    }

    // gi for t=0 (ks==0 lanes use them)
    float gR[3][2], gN[3][2];
    if (ks == 0) {
        #pragma unroll
        for (int sub = 0; sub < 3; ++sub)
            #pragma unroll
            for (int bb = 0; bb < 2; ++bb) {
                const size_t mi = ((size_t)(b0 + bb) * Td) * Hd + gbase[sub];
                gR[sub][bb] = giR[mi];
                gN[sub][bb] = out[mi];
            }
    }

    for (int t = 0; t < Td; ++t) {
        // 1. reset own slice of region (t+2)%4 (acks overlap poll+compute)
        if (tid < 2 * GPW) {
            const int bb = tid / GPW, kk = tid % GPW;
            __hip_atomic_store(ringp + ((t + 2) & 3) * RVALS + bb * Hd + s * GPW + kk,
                               SENT_U, __ATOMIC_RELAXED, __HIP_MEMORY_SCOPE_AGENT);
        }

        // 2. poll-load h_t: 6 words/thread, all reloaded per round (1 RT/round)
        const unsigned* src = ringp + (t & 3) * RVALS;
        unsigned v[6];
        for (;;) {
            unsigned nv[6];
            #pragma unroll
            for (int i = 0; i < 6; ++i)
                nv[i] = __hip_atomic_load(src + tid + i * 256, __ATOMIC_RELAXED,
                                          __HIP_MEMORY_SCOPE_AGENT);
            unsigned bad = 0;
            #pragma unroll
            for (int i = 0; i < 6; ++i) bad |= (nv[i] == SENT_U) ? 1u : 0u;
            if (!bad) {
                #pragma unroll
                for (int i = 0; i < 6; ++i) v[i] = nv[i];
                break;
            }
            __builtin_amdgcn_s_sleep(1);
        }
        float* hsl = &hs[t & 1][0][0];
        #pragma unroll
        for (int i = 0; i < 6; ++i) hsl[tid + i * 256] = __uint_as_float(v[i]);
        __syncthreads();

        // prefetch gi[t+1] (plain cached loads, overlap compute)
        float gR2[3][2], gN2[3][2];
        if (ks == 0 && t + 1 < Td) {
            #pragma unroll
            for (int sub = 0; sub < 3; ++sub)
                #pragma unroll
                for (int bb = 0; bb < 2; ++bb) {
                    const size_t mi = ((size_t)(b0 + bb) * Td + (t + 1)) * Hd + gbase[sub];
                    gR2[sub][bb] = giR[mi];
                    gN2[sub][bb] = out[mi];
                }
        }

        // 3. matvec: 3 subtiles x 2 batches x 48 k x 2 gates
        float aR[3][2], aN[3][2];
        #pragma unroll
        for (int sub = 0; sub < 3; ++sub)
            #pragma unroll
            for (int bb = 0; bb < 2; ++bb) { aR[sub][bb] = 0.f; aN[sub][bb] = 0.f; }
        #pragma unroll
        for (int bb = 0; bb < 2; ++bb) {
            #pragma unroll
            for (int j = 0; j < 12; ++j) {
                float4 h4 = *(const float4*)&hs[t & 1][bb][(ks << 2) + (j << 6)];
                #pragma unroll
                for (int sub = 0; sub < 3; ++sub) {
                    aR[sub][bb] = fmaf(h4.x, wr[sub][j*4+0], aR[sub][bb]);
                    aN[sub][bb] = fmaf(h4.x, wn[sub][j*4+0], aN[sub][bb]);
                    aR[sub][bb] = fmaf(h4.y, wr[sub][j*4+1], aR[sub][bb]);
                    aN[sub][bb] = fmaf(h4.y, wn[sub][j*4+1], aN[sub][bb]);
                    aR[sub][bb] = fmaf(h4.z, wr[sub][j*4+2], aR[sub][bb]);
                    aN[sub][bb] = fmaf(h4.z, wn[sub][j*4+2], aN[sub][bb]);
                    aR[sub][bb] = fmaf(h4.w, wr[sub][j*4+3], aR[sub][bb]);
                    aN[sub][bb] = fmaf(h4.w, wn[sub][j*4+3], aN[sub][bb]);
                }
            }
        }
        #pragma unroll
        for (int sub = 0; sub < 3; ++sub)
            #pragma unroll
            for (int bb = 0; bb < 2; ++bb)
                #pragma unroll
                for (int off = 8; off >= 1; off >>= 1) {
                    aR[sub][bb] += __shfl_xor(aR[sub][bb], off);
                    aN[sub][bb] += __shfl_xor(aN[sub][bb], off);
                }

        // order reset acks (and all prior vmem) before the produce stores
        asm volatile("s_waitcnt vmcnt(0)" ::: "memory");

        // 4. produce h_{t+1} into region (t+1)%4, then out[:,t]
        if (ks == 0) {
            unsigned* dst = ringp + ((t + 1) & 3) * RVALS;
            float hn[3][2];
            #pragma unroll
            for (int sub = 0; sub < 3; ++sub)
                #pragma unroll
                for (int bb = 0; bb < 2; ++bb) {
                    const float r = 1.f / (1.f + __expf(-(gR[sub][bb] + aR[sub][bb] + br[sub])));
                    const float h = tanhf(gN[sub][bb] + r * (aN[sub][bb] + bn[sub]));
                    hn[sub][bb] = h;
                    __hip_atomic_store(dst + bb * Hd + gbase[sub], __float_as_uint(h),
                                       __ATOMIC_RELAXED, __HIP_MEMORY_SCOPE_AGENT);
                }
            #pragma unroll
            for (int sub = 0; sub < 3; ++sub)
                #pragma unroll
                for (int bb = 0; bb < 2; ++bb)
                    out[((size_t)(b0 + bb) * Td + t) * Hd + gbase[sub]] = hn[sub][bb];
            #pragma unroll
            for (int sub = 0; sub < 3; ++sub)
                #pragma unroll
                for (int bb = 0; bb < 2; ++bb) { gR[sub][bb] = gR2[sub][bb]; gN[sub][bb] = gN2[sub][bb]; }
        }
        __syncthreads();   // parity-buffer safety: no wave may run 2 steps ahead
    }
}

extern "C" void kernel_launch(void* const* d_in, const int* in_sizes, int n_in,
                              void* d_out, int out_size, void* d_ws, size_t ws_size,
                              hipStream_t stream) {
    const float* input  = (const float*)d_in[0];
    const float* hidden = (const float*)d_in[1];
    const float* Wih    = (const float*)d_in[2];
    const float* Whh    = (const float*)d_in[3];
    const float* bih    = (const float*)d_in[4];
    const float* bhh    = (const float*)d_in[5];
    float* out = (float*)d_out;

    // ws layout: gi_r (M*H f32) | sentinel ring (16 pairs x 4 x 1536 u32)
    float*    giR  = (float*)d_ws;
    unsigned* ring = (unsigned*)(giR + (size_t)Md * Hd);

    k_init<<<(NPAIR * RINGD * RVALS) / 256, 256, 0, stream>>>(hidden, ring);
    k_gemm<<<512 * 12, 256, 0, stream>>>(input, Wih, bih, giR, out);
    k_scan<<<NPAIR * SPW, 256, 0, stream>>>(Whh, bhh, giR, out, ring);
}